// Round 15
// baseline (1258.977 us; speedup 1.0000x reference)
//
#include <hip/hip_runtime.h>
#include <hip/hip_bf16.h>

// FNO2D: B=8, C=64, H=W=256, MODES=20.
// Spectral conv as partial DFTs (only 40x20 modes used). In-place activations.
// BN+ReLU fused into next-layer dftw (l=1..3, write-back) and into fc12.
// speclin: r8-optimal register-tile GEMM. dftw: 8-rows/thread (vector transpose,
// 2x fewer LDS ops per FMA). fc12: h-pair 512-thread version.

__device__ __forceinline__ void gll16(const float* gsrc, float* ldst) {
    __builtin_amdgcn_global_load_lds(
        (const __attribute__((address_space(1))) void*)gsrc,
        (__attribute__((address_space(3))) void*)ldst, 16, 0, 0);
}

__device__ __forceinline__ unsigned bfp(float x) {          // f32 -> bf16 bits (RNE)
    unsigned u = __float_as_uint(x);
    return (u + 0x7fffu + ((u >> 16) & 1u)) >> 16;
}

// ---------------------------------------------------------------- init tables
__global__ __launch_bounds__(256) void init_k(const float* __restrict__ cw,
                                              float* __restrict__ costab, float* __restrict__ sintab,
                                              float* __restrict__ EAt, float* __restrict__ Tw,
                                              float* __restrict__ cwT, float* __restrict__ stats) {
    int idx = blockIdx.x * 256 + threadIdx.x;
    const float PH = 6.28318530717958647692f / 256.f;
    if (idx < 256) {
        float s, c; sincosf(idx * PH, &s, &c);
        costab[idx] = c; sintab[idx] = s;
    } else if (idx < 256 + 10240) {            // EAt[n][w]: forward DFT along W (transposed)
        int e = idx - 256;
        int n = e >> 8, w = e & 255, ky = n >> 1;
        int r = (ky * w) & 255;
        float s, c; sincosf(r * PH, &s, &c);
        EAt[e] = (n & 1) ? -s : c;
    } else if (idx < 256 + 20480) {            // Tw[kp][w]: irfft along W (ortho, Im(z0) dropped)
        int e = idx - 10496;
        int kp = e >> 8, w = e & 255;
        int ky = kp >> 1, p = kp & 1;
        int r = (ky * w) & 255;
        float s, c; sincosf(r * PH, &s, &c);
        float v;
        if (ky == 0) v = p ? 0.f : (1.f / 16.f);
        else         v = p ? (-2.f / 16.f) * s : (2.f / 16.f) * c;
        Tw[e] = v;
    } else if (idx < 256 + 20480 + 16384) {    // cwT[l][i][o] = cw[l][o][i]
        int e = idx - 20736;
        int l = e >> 12, r2 = e & 4095;
        int i = r2 >> 6, o = r2 & 63;
        cwT[e] = cw[(l << 12) + (o << 6) + i];
    } else if (idx < 256 + 20480 + 16384 + 2048) {
        stats[idx - 37120] = 0.f;              // zero BN-stats accumulators (4 layers x 512)
    }
}

// ---------------------- one-time weight transpose: W[l][i][o][x][y] -> bf16 [t2][xy][i][o]
__global__ __launch_bounds__(256) void wtrans_k(const float* __restrict__ sw1,
                                                const float* __restrict__ sw2,
                                                unsigned int* __restrict__ wt) {
    int gid = blockIdx.x * 4 + (threadIdx.x >> 6);   // 0..12799
    int o = threadIdx.x & 63;
    int xyc = gid % 25;
    int i = (gid / 25) & 63;
    int t2 = gid / 1600;                             // 0..7
    const float* src = ((t2 & 1) ? sw2 : sw1) + (t2 >> 1) * 3276800;
    const float* sp = src + ((i * 64 + o) * 400 + xyc * 16) * 2;
    unsigned int* dp = wt + (size_t)(t2 * 400 + xyc * 16) * 4096 + i * 64 + o;
#pragma unroll
    for (int j = 0; j < 16; ++j) {
        float re = sp[2 * j], im = sp[2 * j + 1];
        dp[(size_t)j * 4096] = bfp(re) | (bfp(im) << 16);
    }
}

// ------------------------------------------------------------------------ fc0
__global__ __launch_bounds__(256) void fc0_k(const float* __restrict__ x,
                                             const float* __restrict__ w,
                                             const float* __restrict__ bias,
                                             float* __restrict__ outb) {
    __shared__ float ws[768];
    __shared__ float bs[64];
    int tid = threadIdx.x;
    for (int i = tid; i < 768; i += 256) ws[i] = w[i];
    if (tid < 64) bs[tid] = bias[tid];
    __syncthreads();
    int pix = blockIdx.x * 256 + tid;           // 0..524287
    int b = pix >> 16, hw = pix & 65535;
    float xv[12];
#pragma unroll
    for (int t = 0; t < 12; ++t) xv[t] = x[pix * 12 + t];
    int base = (b << 22) + hw;
    for (int c = 0; c < 64; ++c) {
        float a = bs[c];
#pragma unroll
        for (int t = 0; t < 12; ++t) a += xv[t] * ws[t * 64 + c];
        outb[base + (c << 16)] = a;
    }
}

// ------------------- stage A: DFT along W (GEMM), fused BN+ReLU (write-back)
// Block = 128 consecutive rows (within one (b,c)). 128 thr: tm 0..15 x 8 rows, tn 0..7 x 5 n.
// Xs transpose via in-register gather -> vector b128 writes; 104 b128 reads / 1280 FMA per chunk.
__global__ __launch_bounds__(128) void dftw_k(float* __restrict__ X,
                                              const float* __restrict__ EAt,
                                              float* __restrict__ T,
                                              const float* __restrict__ statsl,
                                              const float* __restrict__ g,
                                              const float* __restrict__ bt,
                                              int fuse) {
    __shared__ __align__(16) float Xs[32 * 132];  // transposed [k][m], stride 132
    __shared__ __align__(16) float Est[40 * 32];  // [n][k] chunk
    int tid = threadIdx.x;
    int tm = tid >> 3, tn = tid & 7;
    int m0 = tm << 3;
    int rowbase = blockIdx.x << 7;
    float sc = 1.f, sh = 0.f;
    if (fuse) {
        int c = (rowbase >> 8) & 63;
        float ssum = statsl[c] + statsl[128 + c] + statsl[256 + c] + statsl[384 + c];
        float ssq  = statsl[64 + c] + statsl[192 + c] + statsl[320 + c] + statsl[448 + c];
        float mean = ssum * (1.f / 524288.f);
        float var = ssq * (1.f / 524288.f) - mean * mean;
        sc = g[c] * rsqrtf(var + 1e-5f);
        sh = bt[c] - mean * sc;
    }
    float acc[8][5];
#pragma unroll
    for (int i = 0; i < 8; ++i)
#pragma unroll
        for (int j = 0; j < 5; ++j) acc[i][j] = 0.f;

#pragma unroll 1
    for (int kc = 0; kc < 256; kc += 32) {
        float4 xv[8];
#pragma unroll
        for (int r = 0; r < 8; ++r) {
            int row = rowbase + m0 + r;
            float4 v = *(const float4*)&X[row * 256 + kc + (tn << 2)];
            if (fuse) {
                v.x = fmaxf(fmaf(v.x, sc, sh), 0.f);
                v.y = fmaxf(fmaf(v.y, sc, sh), 0.f);
                v.z = fmaxf(fmaf(v.z, sc, sh), 0.f);
                v.w = fmaxf(fmaf(v.w, sc, sh), 0.f);
                *(float4*)&X[row * 256 + kc + (tn << 2)] = v;
            }
            xv[r] = v;
        }
        __syncthreads();
#pragma unroll
        for (int e = 0; e < 4; ++e) {
            int k = (tn << 2) + e;
            float4 w0, w1;
            w0.x = ((const float*)&xv[0])[e]; w0.y = ((const float*)&xv[1])[e];
            w0.z = ((const float*)&xv[2])[e]; w0.w = ((const float*)&xv[3])[e];
            w1.x = ((const float*)&xv[4])[e]; w1.y = ((const float*)&xv[5])[e];
            w1.z = ((const float*)&xv[6])[e]; w1.w = ((const float*)&xv[7])[e];
            *(float4*)&Xs[k * 132 + m0] = w0;
            *(float4*)&Xs[k * 132 + m0 + 4] = w1;
        }
        for (int i = tid; i < 1280; i += 128) Est[i] = EAt[((i >> 5) << 8) + kc + (i & 31)];
        __syncthreads();
#pragma unroll 1
        for (int k4 = 0; k4 < 8; ++k4) {
            float4 e0 = *(const float4*)&Est[(tn * 5 + 0) * 32 + (k4 << 2)];
            float4 e1 = *(const float4*)&Est[(tn * 5 + 1) * 32 + (k4 << 2)];
            float4 e2 = *(const float4*)&Est[(tn * 5 + 2) * 32 + (k4 << 2)];
            float4 e3 = *(const float4*)&Est[(tn * 5 + 3) * 32 + (k4 << 2)];
            float4 e4 = *(const float4*)&Est[(tn * 5 + 4) * 32 + (k4 << 2)];
#pragma unroll
            for (int c2 = 0; c2 < 4; ++c2) {
                int k = (k4 << 2) + c2;
                float4 xa = *(const float4*)&Xs[k * 132 + m0];
                float4 xb = *(const float4*)&Xs[k * 132 + m0 + 4];
                float ev0 = ((const float*)&e0)[c2];
                float ev1 = ((const float*)&e1)[c2];
                float ev2 = ((const float*)&e2)[c2];
                float ev3 = ((const float*)&e3)[c2];
                float ev4 = ((const float*)&e4)[c2];
                acc[0][0] += xa.x * ev0; acc[1][0] += xa.y * ev0; acc[2][0] += xa.z * ev0; acc[3][0] += xa.w * ev0;
                acc[4][0] += xb.x * ev0; acc[5][0] += xb.y * ev0; acc[6][0] += xb.z * ev0; acc[7][0] += xb.w * ev0;
                acc[0][1] += xa.x * ev1; acc[1][1] += xa.y * ev1; acc[2][1] += xa.z * ev1; acc[3][1] += xa.w * ev1;
                acc[4][1] += xb.x * ev1; acc[5][1] += xb.y * ev1; acc[6][1] += xb.z * ev1; acc[7][1] += xb.w * ev1;
                acc[0][2] += xa.x * ev2; acc[1][2] += xa.y * ev2; acc[2][2] += xa.z * ev2; acc[3][2] += xa.w * ev2;
                acc[4][2] += xb.x * ev2; acc[5][2] += xb.y * ev2; acc[6][2] += xb.z * ev2; acc[7][2] += xb.w * ev2;
                acc[0][3] += xa.x * ev3; acc[1][3] += xa.y * ev3; acc[2][3] += xa.z * ev3; acc[3][3] += xa.w * ev3;
                acc[4][3] += xb.x * ev3; acc[5][3] += xb.y * ev3; acc[6][3] += xb.z * ev3; acc[7][3] += xb.w * ev3;
                acc[0][4] += xa.x * ev4; acc[1][4] += xa.y * ev4; acc[2][4] += xa.z * ev4; acc[3][4] += xa.w * ev4;
                acc[4][4] += xb.x * ev4; acc[5][4] += xb.y * ev4; acc[6][4] += xb.z * ev4; acc[7][4] += xb.w * ev4;
            }
        }
    }
#pragma unroll
    for (int r = 0; r < 8; ++r) {
        int row = rowbase + m0 + r;
#pragma unroll
        for (int j = 0; j < 5; ++j) T[row * 40 + tn * 5 + j] = acc[r][j];
    }
}

// --------------- stage B: DFT along H (256 -> 40 rows), 4-way h-split
__global__ __launch_bounds__(1024) void dfth_k(const float* __restrict__ T,
                                               const float* __restrict__ ct, const float* __restrict__ st,
                                               float* __restrict__ XF) {
    __shared__ __align__(16) float Ts[10240];
    __shared__ float cts[256], sts[256];
    __shared__ float part[3][1600];
    int tid = threadIdx.x;
    int bc = blockIdx.x;
    for (int i = tid; i < 10240; i += 1024) Ts[i] = T[bc * 10240 + i];
    if (tid < 256) { cts[tid] = ct[tid]; sts[tid] = st[tid]; }
    __syncthreads();
    int gq = tid >> 8, t2 = tid & 255;
    float ar0 = 0, ai0 = 0, ar1 = 0, ai1 = 0, ar2 = 0, ai2 = 0, ar3 = 0, ai3 = 0;
    int kxi = t2 / 5, kyg = t2 % 5;
    if (t2 < 200) {
        int kxa = kxi < 20 ? kxi : kxi + 216;
        int h0 = gq << 6;
        int r = (kxa * h0) & 255;
#pragma unroll 1
        for (int hh = 0; hh < 64; ++hh) {
            int h = h0 + hh;
            float cc = cts[r], sv = sts[r];
            r = (r + kxa) & 255;
            float4 v0 = *(const float4*)&Ts[h * 40 + (kyg << 3)];
            float4 v1 = *(const float4*)&Ts[h * 40 + (kyg << 3) + 4];
            ar0 += v0.x * cc + v0.y * sv;  ai0 += v0.y * cc - v0.x * sv;
            ar1 += v0.z * cc + v0.w * sv;  ai1 += v0.w * cc - v0.z * sv;
            ar2 += v1.x * cc + v1.y * sv;  ai2 += v1.y * cc - v1.x * sv;
            ar3 += v1.z * cc + v1.w * sv;  ai3 += v1.w * cc - v1.z * sv;
        }
        if (gq) {
            float* p = &part[gq - 1][t2 * 8];
            p[0] = ar0; p[1] = ai0; p[2] = ar1; p[3] = ai1;
            p[4] = ar2; p[5] = ai2; p[6] = ar3; p[7] = ai3;
        }
    }
    __syncthreads();
    if (gq == 0 && t2 < 200) {
#pragma unroll
        for (int j = 0; j < 3; ++j) {
            const float* p = &part[j][t2 * 8];
            ar0 += p[0]; ai0 += p[1]; ar1 += p[2]; ai1 += p[3];
            ar2 += p[4]; ai2 += p[5]; ar3 += p[6]; ai3 += p[7];
        }
        int b = bc >> 6, c = bc & 63;
        const float s = 1.f / 256.f;
        int A = (b * 40 + kxi) * 20 + (kyg << 2);
        float2* O = (float2*)XF;
        O[(A + 0) * 64 + c] = make_float2(ar0 * s, ai0 * s);
        O[(A + 1) * 64 + c] = make_float2(ar1 * s, ai1 * s);
        O[(A + 2) * 64 + c] = make_float2(ar2 * s, ai2 * s);
        O[(A + 3) * 64 + c] = make_float2(ar3 * s, ai3 * s);
    }
}

// ---------------------------------------------------------------- mode einsum
__global__ __launch_bounds__(512) void eins_t_k(const float* __restrict__ XF,
                                                const unsigned int* __restrict__ wtl,
                                                float* __restrict__ YF) {
    __shared__ float xfs[1024];
    int tid = threadIdx.x;
    int x = blockIdx.x / 20, y = blockIdx.x % 20;
    for (int i = tid; i < 1024; i += 512) {
        int b = i >> 7, rr = i & 127;
        xfs[i] = XF[(b * 40 + x) * 2560 + y * 128 + rr];
    }
    __syncthreads();
    int b = tid >> 6, o = tid & 63;
    const unsigned int* wp = wtl + (size_t)(((x < 20 ? 0 : 400) + (x % 20) * 20 + y)) * 4096 + o;
    float ar = 0.f, ai = 0.f;
#pragma unroll 8
    for (int i = 0; i < 64; ++i) {
        unsigned int wv = wp[i << 6];
        float wr = __uint_as_float(wv << 16);
        float wi = __uint_as_float(wv & 0xffff0000u);
        float xr = xfs[(b << 7) + (i << 1)];
        float xi = xfs[(b << 7) + (i << 1) + 1];
        ar += xr * wr - xi * wi;
        ai += xr * wi + xi * wr;
    }
    ((float2*)YF)[((b * 40 + x) * 20 + y) * 64 + o] = make_float2(ar, ai);
}

__global__ __launch_bounds__(512) void eins_k(const float* __restrict__ XF,
                                              const float* __restrict__ w1, const float* __restrict__ w2,
                                              float* __restrict__ YF) {
    __shared__ float xfs[1024];
    int tid = threadIdx.x;
    int x = blockIdx.x / 20, y = blockIdx.x % 20;
    for (int i = tid; i < 1024; i += 512) {
        int b = i >> 7, rr = i & 127;
        xfs[i] = XF[(b * 40 + x) * 2560 + y * 128 + rr];
    }
    __syncthreads();
    int b = tid >> 6, o = tid & 63;
    const float* wp = (x < 20) ? (w1 + (x * 20 + y) * 2) : (w2 + ((x - 20) * 20 + y) * 2);
    float ar = 0.f, ai = 0.f;
#pragma unroll 8
    for (int i = 0; i < 64; ++i) {
        float2 wv = *(const float2*)&wp[(i * 64 + o) * 800];
        float xr = xfs[(b << 7) + (i << 1)];
        float xi = xfs[(b << 7) + (i << 1) + 1];
        ar += xr * wv.x - xi * wv.y;
        ai += xr * wv.y + xi * wv.x;
    }
    ((float2*)YF)[((b * 40 + x) * 20 + y) * 64 + o] = make_float2(ar, ai);
}

// ------------------------------------ stage C: inverse (full complex) DFT along H
__global__ __launch_bounds__(256) void idfth_k(const float* __restrict__ YF,
                                               const float* __restrict__ ct, const float* __restrict__ st,
                                               float* __restrict__ Z) {
    __shared__ __align__(16) float yfs[1600];
    __shared__ float cts[256], sts[256];
    int tid = threadIdx.x;
    int bc = blockIdx.x;
    int b = bc >> 6, co = bc & 63;
    for (int i = tid; i < 800; i += 256) {
        int kx = i / 20, ky = i % 20;
        float2 v = ((const float2*)YF)[((b * 40 + kx) * 20 + ky) * 64 + co];
        yfs[kx * 40 + 2 * ky] = v.x;
        yfs[kx * 40 + 2 * ky + 1] = v.y;
    }
    cts[tid] = ct[tid]; sts[tid] = st[tid];
    __syncthreads();
    int h = tid;
    float accr[20], acci[20];
#pragma unroll
    for (int q = 0; q < 20; ++q) { accr[q] = 0.f; acci[q] = 0.f; }
#pragma unroll 1
    for (int kxi = 0; kxi < 40; ++kxi) {
        int kxa = kxi < 20 ? kxi : kxi + 216;
        int r = (kxa * h) & 255;
        float cc = cts[r], sv = sts[r];
#pragma unroll
        for (int q = 0; q < 10; ++q) {
            float4 v = *(const float4*)&yfs[kxi * 40 + (q << 2)];
            accr[2 * q]     += v.x * cc - v.y * sv;  acci[2 * q]     += v.x * sv + v.y * cc;
            accr[2 * q + 1] += v.z * cc - v.w * sv;  acci[2 * q + 1] += v.z * sv + v.w * cc;
        }
    }
    const float s = 1.f / 16.f;
    int base = (bc * 256 + h) * 40;
#pragma unroll
    for (int q = 0; q < 10; ++q) {
        float4 o4;
        o4.x = accr[2 * q] * s;     o4.y = acci[2 * q] * s;
        o4.z = accr[2 * q + 1] * s; o4.w = acci[2 * q + 1] * s;
        *(float4*)&Z[base + (q << 2)] = o4;
    }
}

// ------------------- stage D fused with 1x1 conv + bias + BN-stats accumulation
#define FMA2(I, AV, J, B4) \
    acc[I][J].x += (AV) * B4.x; acc[I][J].y += (AV) * B4.y; \
    acc[I][J].z += (AV) * B4.z; acc[I][J].w += (AV) * B4.w;

#define FMA_COL(J, B4) \
    FMA2(0, a0.x, J, B4) FMA2(1, a0.y, J, B4) FMA2(2, a0.z, J, B4) FMA2(3, a0.w, J, B4) \
    FMA2(4, a1.x, J, B4) FMA2(5, a1.y, J, B4) FMA2(6, a1.z, J, B4) FMA2(7, a1.w, J, B4)

#define FMA_COLU(J, B4) \
    FMA2(0, au0.x, J, B4) FMA2(1, au0.y, J, B4) FMA2(2, au0.z, J, B4) FMA2(3, au0.w, J, B4) \
    FMA2(4, au1.x, J, B4) FMA2(5, au1.y, J, B4) FMA2(6, au1.z, J, B4) FMA2(7, au1.w, J, B4)

#define FMA_COLD(J, B4) \
    FMA2(0, ad0.x, J, B4) FMA2(1, ad0.y, J, B4) FMA2(2, ad0.z, J, B4) FMA2(3, ad0.w, J, B4) \
    FMA2(4, ad1.x, J, B4) FMA2(5, ad1.y, J, B4) FMA2(6, ad1.z, J, B4) FMA2(7, ad1.w, J, B4)

__global__ __launch_bounds__(256) void speclin_k(const float* __restrict__ hin,
                                                 const float* __restrict__ Z,
                                                 const float* __restrict__ cwTl,
                                                 const float* __restrict__ Tw,
                                                 const float* __restrict__ cbl,
                                                 float* __restrict__ pre,
                                                 float* __restrict__ statsl) {
    __shared__ __align__(16) float As[64 * 68];      // cw^T [i][o] (17.4 KB)
    __shared__ __align__(16) float Zs[80 * 64];      // [r*40+kp][o] (20 KB)
    __shared__ __align__(16) float Bs[2][4096];      // dbuf 8k x 512n (32 KB)
    int tid = threadIdx.x;
    int bid = blockIdx.x;
    int b = bid >> 7, hp = bid & 127;
    int h0 = hp << 1;
    int to = tid >> 5, tw = tid & 31;
    int o0 = to << 3;

#pragma unroll
    for (int t = 0; t < 4; ++t) {
        int i4 = tid + (t << 8);                     // 0..1023
        float4 v = *(const float4*)&cwTl[i4 << 2];
        float* d = &As[(i4 >> 4) * 68 + ((i4 & 15) << 2)];
        d[0] = v.x; d[1] = v.y; d[2] = v.z; d[3] = v.w;
    }
#pragma unroll
    for (int t = 0; t < 5; ++t) {
        int i4 = tid + (t << 8);                     // 0..1279
        int q = i4 % 10;
        int u = i4 / 10;                             // 0..127
        int o = u & 63, r = u >> 6;
        float4 v = *(const float4*)&Z[(((b << 6) + o) * 256 + h0 + r) * 40 + (q << 2)];
        int base = ((r * 40 + (q << 2)) << 6) + o;
        Zs[base]       = v.x;
        Zs[base + 64]  = v.y;
        Zs[base + 128] = v.z;
        Zs[base + 192] = v.w;
    }
    const float* hrow = hin + (size_t)((((b << 6) << 8) + h0) << 8);
#pragma unroll
    for (int t = 0; t < 4; ++t) {                    // Bs chunk 0 via DMA
        int i4 = tid + (t << 8);                     // 0..1023
        int k = i4 >> 7, n4 = i4 & 127, r = n4 >> 6, w4 = n4 & 63;
        gll16(&hrow[(k << 16) + (r << 8) + (w4 << 2)], &Bs[0][i4 << 2]);
    }
    __syncthreads();

    float4 acc[8][4];
#pragma unroll
    for (int i = 0; i < 8; ++i)
#pragma unroll
        for (int j = 0; j < 4; ++j) acc[i][j] = make_float4(0.f, 0.f, 0.f, 0.f);

    int cur = 0;
#pragma unroll 1
    for (int ch = 0; ch < 8; ++ch) {
        if (ch < 7) {
#pragma unroll
            for (int t = 0; t < 4; ++t) {
                int i4 = tid + (t << 8);
                int k = i4 >> 7, n4 = i4 & 127, r = n4 >> 6, w4 = n4 & 63;
                gll16(&hrow[((((ch + 1) << 3) + k) << 16) + (r << 8) + (w4 << 2)],
                      &Bs[cur ^ 1][i4 << 2]);
            }
        } else {
#pragma unroll
            for (int t = 0; t < 2; ++t) {
                int i4 = tid + (t << 8);
                gll16(&Tw[i4 << 2], &Bs[cur ^ 1][i4 << 2]);
            }
        }
        const float* Bc = Bs[cur];
        const float* Ac = &As[(ch << 3) * 68 + o0];
#pragma unroll 1
        for (int kk = 0; kk < 8; ++kk) {
            float4 a0 = *(const float4*)&Ac[kk * 68];
            float4 a1 = *(const float4*)&Ac[kk * 68 + 4];
            float4 b0 = *(const float4*)&Bc[(kk << 9) + (tw << 2)];
            float4 b1 = *(const float4*)&Bc[(kk << 9) + 128 + (tw << 2)];
            FMA_COL(0, b0)
            FMA_COL(1, b1)
            float4 b2 = *(const float4*)&Bc[(kk << 9) + 256 + (tw << 2)];
            float4 b3 = *(const float4*)&Bc[(kk << 9) + 384 + (tw << 2)];
            FMA_COL(2, b2)
            FMA_COL(3, b3)
        }
        __syncthreads();
        cur ^= 1;
    }

#pragma unroll 1
    for (int ch = 0; ch < 5; ++ch) {
        if (ch < 4) {
#pragma unroll
            for (int t = 0; t < 2; ++t) {
                int i4 = tid + (t << 8);
                gll16(&Tw[(((ch + 1) << 3) << 8) + (i4 << 2)], &Bs[cur ^ 1][i4 << 2]);
            }
        }
        const float* Bc = Bs[cur];
#pragma unroll 1
        for (int kk = 0; kk < 8; ++kk) {
            int kp = (ch << 3) + kk;
            float4 b0 = *(const float4*)&Bc[(kk << 8) + (tw << 2)];
            float4 b1 = *(const float4*)&Bc[(kk << 8) + 128 + (tw << 2)];
            float4 au0 = *(const float4*)&Zs[(kp << 6) + o0];
            float4 au1 = *(const float4*)&Zs[(kp << 6) + o0 + 4];
            FMA_COLU(0, b0)
            FMA_COLU(1, b1)
            float4 ad0 = *(const float4*)&Zs[((40 + kp) << 6) + o0];
            float4 ad1 = *(const float4*)&Zs[((40 + kp) << 6) + o0 + 4];
            FMA_COLD(2, b0)
            FMA_COLD(3, b1)
        }
        __syncthreads();
        cur ^= 1;
    }

    float* srep = statsl + ((bid & 3) << 7);
#pragma unroll
    for (int i = 0; i < 8; ++i) {
        float cbv = cbl[o0 + i];
        float sum = 0.f, sq = 0.f;
#pragma unroll
        for (int j = 0; j < 4; ++j) {
            float4 v = acc[i][j];
            v.x += cbv; v.y += cbv; v.z += cbv; v.w += cbv;
            int row = h0 + (j >> 1);
            int wc = ((j & 1) << 7) + (tw << 2);
            *(float4*)&pre[(size_t)((((b << 6) + o0 + i) << 8) + row) * 256 + wc] = v;
            sum += v.x + v.y + v.z + v.w;
            sq  += v.x * v.x + v.y * v.y + v.z * v.z + v.w * v.w;
        }
        sum += __shfl_xor(sum, 1);  sq += __shfl_xor(sq, 1);
        sum += __shfl_xor(sum, 2);  sq += __shfl_xor(sq, 2);
        sum += __shfl_xor(sum, 4);  sq += __shfl_xor(sq, 4);
        sum += __shfl_xor(sum, 8);  sq += __shfl_xor(sq, 8);
        sum += __shfl_xor(sum, 16); sq += __shfl_xor(sq, 16);
        if ((tid & 31) == 0) {
            atomicAdd(&srep[o0 + i], sum);
            atomicAdd(&srep[64 + o0 + i], sq);
        }
    }
}

// ----------------- fc1+relu+fc2, layer-3 BN folded; h-pair, 512 threads
// Block = (b, h-pair). Thread (to 0..15, tw 0..31): 8 d x 16 n (n over 512 = 2 rows).
__global__ __launch_bounds__(512) void fc12_k(const float* __restrict__ hin,
                                              const float* __restrict__ statsl,
                                              const float* __restrict__ g,
                                              const float* __restrict__ bt,
                                              const float* __restrict__ w1, const float* __restrict__ b1,
                                              const float* __restrict__ w2, const float* __restrict__ b2,
                                              float* __restrict__ out) {
    __shared__ __align__(16) float As[64 * 128];   // sc_c * fc1_w[c][d]  32 KB
    __shared__ __align__(16) float Bs[2][4096];    // dbuf 8k x 512n      32 KB
    __shared__ float scs[64], shs[64], bias2[128];
    int tid = threadIdx.x;
    int bid = blockIdx.x;
    int b = bid >> 7, hp = bid & 127;
    int h0 = hp << 1;
    int to = tid >> 5, tw = tid & 31;
    int d0 = to << 3;

    if (tid < 64) {
        float ssum = statsl[tid] + statsl[128 + tid] + statsl[256 + tid] + statsl[384 + tid];
        float ssq  = statsl[64 + tid] + statsl[192 + tid] + statsl[320 + tid] + statsl[448 + tid];
        float mean = ssum * (1.f / 524288.f);
        float var = ssq * (1.f / 524288.f) - mean * mean;
        float s = g[tid] * rsqrtf(var + 1e-5f);
        scs[tid] = s; shs[tid] = bt[tid] - mean * s;
    }
    __syncthreads();
    for (int i = tid; i < 8192; i += 512) As[i] = w1[i] * scs[i >> 7];
    if (tid < 128) {
        float a = b1[tid];
        for (int c = 0; c < 64; ++c) a += shs[c] * w1[c * 128 + tid];
        bias2[tid] = a;
    }
    const float* hrow = hin + (size_t)((((b << 6) << 8) + h0) << 8);
#pragma unroll
    for (int t = 0; t < 2; ++t) {                  // Bs chunk 0 via DMA
        int i4 = tid + (t << 9);                   // 0..1023
        int k = i4 >> 7, n4 = i4 & 127, r = n4 >> 6, w4 = n4 & 63;
        gll16(&hrow[(k << 16) + (r << 8) + (w4 << 2)], &Bs[0][i4 << 2]);
    }
    __syncthreads();

    float4 acc[8][4];
#pragma unroll
    for (int i = 0; i < 8; ++i)
#pragma unroll
        for (int j = 0; j < 4; ++j) acc[i][j] = make_float4(0.f, 0.f, 0.f, 0.f);

    int cur = 0;
#pragma unroll 1
    for (int ch = 0; ch < 8; ++ch) {
        if (ch < 7) {
#pragma unroll
            for (int t = 0; t < 2; ++t) {
                int i4 = tid + (t << 9);
                int k = i4 >> 7, n4 = i4 & 127, r = n4 >> 6, w4 = n4 & 63;
                gll16(&hrow[((((ch + 1) << 3) + k) << 16) + (r << 8) + (w4 << 2)],
                      &Bs[cur ^ 1][i4 << 2]);
            }
        }
        const float* Bc = Bs[cur];
#pragma unroll 1
        for (int kk = 0; kk < 8; ++kk) {
            int gk = (ch << 3) + kk;
            float4 a0 = *(const float4*)&As[(gk << 7) + d0];
            float4 a1 = *(const float4*)&As[(gk << 7) + d0 + 4];
            float4 b0 = *(const float4*)&Bc[(kk << 9) + (tw << 2)];
            float4 b1 = *(const float4*)&Bc[(kk << 9) + 128 + (tw << 2)];
            FMA_COL(0, b0)
            FMA_COL(1, b1)
            float4 b2 = *(const float4*)&Bc[(kk << 9) + 256 + (tw << 2)];
            float4 b3 = *(const float4*)&Bc[(kk << 9) + 384 + (tw << 2)];
            FMA_COL(2, b2)
            FMA_COL(3, b3)
        }
        __syncthreads();
        cur ^= 1;
    }

    // epilogue: relu + fc2 partial; reduce over 16 to-groups.
    float bb[8], wv[8];
#pragma unroll
    for (int i = 0; i < 8; ++i) { bb[i] = bias2[d0 + i]; wv[i] = w2[d0 + i]; }
    float4 p[4];
#pragma unroll
    for (int j = 0; j < 4; ++j) {
        float4 v = make_float4(0.f, 0.f, 0.f, 0.f);
#pragma unroll
        for (int i = 0; i < 8; ++i) {
            v.x += fmaxf(acc[i][j].x + bb[i], 0.f) * wv[i];
            v.y += fmaxf(acc[i][j].y + bb[i], 0.f) * wv[i];
            v.z += fmaxf(acc[i][j].z + bb[i], 0.f) * wv[i];
            v.w += fmaxf(acc[i][j].w + bb[i], 0.f) * wv[i];
        }
        // combine the two to-groups within this wave
        v.x += __shfl_xor(v.x, 32); v.y += __shfl_xor(v.y, 32);
        v.z += __shfl_xor(v.z, 32); v.w += __shfl_xor(v.w, 32);
        p[j] = v;
    }
    float* red = &Bs[0][0];                         // both B buffers free now (4096 floats)
    int wave = tid >> 6;
    if ((tid & 32) == 0) {                          // lane < 32 of each wave
#pragma unroll
        for (int j = 0; j < 4; ++j)
            *(float4*)&red[(wave << 9) + (j << 7) + (tw << 2)] = p[j];
    }
    __syncthreads();
    {
        int n = tid;                                // 0..511
        float s2 = b2[0];
#pragma unroll
        for (int w8 = 0; w8 < 8; ++w8) s2 += red[(w8 << 9) + n];
        int r = n >> 8, w = n & 255;
        out[(b * 256 + h0 + r) * 256 + w] = s2;
    }
}

// ------------------------------------------------------------------- launcher
extern "C" void kernel_launch(void* const* d_in, const int* in_sizes, int n_in,
                              void* d_out, int out_size, void* d_ws, size_t ws_size,
                              hipStream_t stream) {
    (void)in_sizes; (void)n_in; (void)out_size;
    const float* x     = (const float*)d_in[0];
    const float* fc0_w = (const float*)d_in[1];
    const float* fc0_b = (const float*)d_in[2];
    const float* sw1   = (const float*)d_in[3];
    const float* sw2   = (const float*)d_in[4];
    const float* cw    = (const float*)d_in[5];
    const float* cb    = (const float*)d_in[6];
    const float* bng   = (const float*)d_in[7];
    const float* bnb   = (const float*)d_in[8];
    const float* fc1_w = (const float*)d_in[9];
    const float* fc1_b = (const float*)d_in[10];
    const float* fc2_w = (const float*)d_in[11];
    const float* fc2_b = (const float*)d_in[12];
    float* out = (float*)d_out;

    float* ws = (float*)d_ws;
    float* hbuf   = ws;                       // 33,554,432  (in-place activations)
    float* tz     = hbuf + 33554432;          // 5,242,880
    float* xf     = tz + 5242880;             // 819,200
    float* yf     = xf + 819200;              // 819,200
    float* costab = yf + 819200;              // 256
    float* sintab = costab + 256;             // 256
    float* EAt    = sintab + 256;             // 10,240
    float* Tw     = EAt + 10240;              // 10,240
    float* cwT    = Tw + 10240;               // 16,384
    float* stats  = cwT + 16384;              // 2,048  (4 layers x 4 replicas x 128)
    unsigned* wt  = (unsigned*)(stats + 2048);         // 13,107,200 u32 (optional)

    size_t base_floats = 40473600 + 2048;     // through stats
    int use_wt = (ws_size >= (base_floats + 13107200ull) * 4ull) ? 1 : 0;

    init_k<<<153, 256, 0, stream>>>(cw, costab, sintab, EAt, Tw, cwT, stats);
    if (use_wt) wtrans_k<<<3200, 256, 0, stream>>>(sw1, sw2, wt);
    fc0_k<<<2048, 256, 0, stream>>>(x, fc0_w, fc0_b, hbuf);

    for (int l = 0; l < 4; ++l) {
        if (l == 0)
            dftw_k<<<1024, 128, 0, stream>>>(hbuf, EAt, tz, stats, bng, bnb, 0);
        else
            dftw_k<<<1024, 128, 0, stream>>>(hbuf, EAt, tz, stats + (l - 1) * 512,
                                             bng + (l - 1) * 64, bnb + (l - 1) * 64, 1);
        dfth_k<<<512, 1024, 0, stream>>>(tz, costab, sintab, xf);
        if (use_wt)
            eins_t_k<<<800, 512, 0, stream>>>(xf, wt + (size_t)l * 2 * 400 * 4096, yf);
        else
            eins_k<<<800, 512, 0, stream>>>(xf, sw1 + l * 3276800, sw2 + l * 3276800, yf);
        idfth_k<<<512, 256, 0, stream>>>(yf, costab, sintab, tz);
        speclin_k<<<1024, 256, 0, stream>>>(hbuf, tz, cwT + l * 4096, Tw, cb + l * 64,
                                            hbuf, stats + l * 512);
    }
    fc12_k<<<1024, 512, 0, stream>>>(hbuf, stats + 3 * 512, bng + 3 * 64, bnb + 3 * 64,
                                     fc1_w, fc1_b, fc2_w, fc2_b, out);
}

// Round 16
// 1192.808 us; speedup vs baseline: 1.0555x; 1.0555x over previous
//
#include <hip/hip_runtime.h>
#include <hip/hip_bf16.h>

// FNO2D: B=8, C=64, H=W=256, MODES=20.
// Spectral conv as partial DFTs (only 40x20 modes used). In-place activations.
// BN+ReLU fused into next-layer dftw (l=1..3, write-back) and into fc12.
// Consolidated best-measured config (round-14, 1204 us): dftw Est-version,
// dfth 4-way h-split, speclin r8-optimal register tile, fc12 256-thread.

__device__ __forceinline__ void gll16(const float* gsrc, float* ldst) {
    __builtin_amdgcn_global_load_lds(
        (const __attribute__((address_space(1))) void*)gsrc,
        (__attribute__((address_space(3))) void*)ldst, 16, 0, 0);
}

__device__ __forceinline__ unsigned bfp(float x) {          // f32 -> bf16 bits (RNE)
    unsigned u = __float_as_uint(x);
    return (u + 0x7fffu + ((u >> 16) & 1u)) >> 16;
}

// ---------------------------------------------------------------- init tables
__global__ __launch_bounds__(256) void init_k(const float* __restrict__ cw,
                                              float* __restrict__ costab, float* __restrict__ sintab,
                                              float* __restrict__ EAt, float* __restrict__ Tw,
                                              float* __restrict__ cwT, float* __restrict__ stats) {
    int idx = blockIdx.x * 256 + threadIdx.x;
    const float PH = 6.28318530717958647692f / 256.f;
    if (idx < 256) {
        float s, c; sincosf(idx * PH, &s, &c);
        costab[idx] = c; sintab[idx] = s;
    } else if (idx < 256 + 10240) {            // EAt[n][w]: forward DFT along W (transposed)
        int e = idx - 256;
        int n = e >> 8, w = e & 255, ky = n >> 1;
        int r = (ky * w) & 255;
        float s, c; sincosf(r * PH, &s, &c);
        EAt[e] = (n & 1) ? -s : c;
    } else if (idx < 256 + 20480) {            // Tw[kp][w]: irfft along W (ortho, Im(z0) dropped)
        int e = idx - 10496;
        int kp = e >> 8, w = e & 255;
        int ky = kp >> 1, p = kp & 1;
        int r = (ky * w) & 255;
        float s, c; sincosf(r * PH, &s, &c);
        float v;
        if (ky == 0) v = p ? 0.f : (1.f / 16.f);
        else         v = p ? (-2.f / 16.f) * s : (2.f / 16.f) * c;
        Tw[e] = v;
    } else if (idx < 256 + 20480 + 16384) {    // cwT[l][i][o] = cw[l][o][i]
        int e = idx - 20736;
        int l = e >> 12, r2 = e & 4095;
        int i = r2 >> 6, o = r2 & 63;
        cwT[e] = cw[(l << 12) + (o << 6) + i];
    } else if (idx < 256 + 20480 + 16384 + 2048) {
        stats[idx - 37120] = 0.f;              // zero BN-stats accumulators (4 layers x 512)
    }
}

// ---------------------- one-time weight transpose: W[l][i][o][x][y] -> bf16 [t2][xy][i][o]
__global__ __launch_bounds__(256) void wtrans_k(const float* __restrict__ sw1,
                                                const float* __restrict__ sw2,
                                                unsigned int* __restrict__ wt) {
    int gid = blockIdx.x * 4 + (threadIdx.x >> 6);   // 0..12799
    int o = threadIdx.x & 63;
    int xyc = gid % 25;
    int i = (gid / 25) & 63;
    int t2 = gid / 1600;                             // 0..7
    const float* src = ((t2 & 1) ? sw2 : sw1) + (t2 >> 1) * 3276800;
    const float* sp = src + ((i * 64 + o) * 400 + xyc * 16) * 2;
    unsigned int* dp = wt + (size_t)(t2 * 400 + xyc * 16) * 4096 + i * 64 + o;
#pragma unroll
    for (int j = 0; j < 16; ++j) {
        float re = sp[2 * j], im = sp[2 * j + 1];
        dp[(size_t)j * 4096] = bfp(re) | (bfp(im) << 16);
    }
}

// ------------------------------------------------------------------------ fc0
__global__ __launch_bounds__(256) void fc0_k(const float* __restrict__ x,
                                             const float* __restrict__ w,
                                             const float* __restrict__ bias,
                                             float* __restrict__ outb) {
    __shared__ float ws[768];
    __shared__ float bs[64];
    int tid = threadIdx.x;
    for (int i = tid; i < 768; i += 256) ws[i] = w[i];
    if (tid < 64) bs[tid] = bias[tid];
    __syncthreads();
    int pix = blockIdx.x * 256 + tid;           // 0..524287
    int b = pix >> 16, hw = pix & 65535;
    float xv[12];
#pragma unroll
    for (int t = 0; t < 12; ++t) xv[t] = x[pix * 12 + t];
    int base = (b << 22) + hw;
    for (int c = 0; c < 64; ++c) {
        float a = bs[c];
#pragma unroll
        for (int t = 0; t < 12; ++t) a += xv[t] * ws[t * 64 + c];
        outb[base + (c << 16)] = a;
    }
}

// ------------------- stage A: DFT along W (GEMM), fused BN+ReLU (write-back)
__global__ __launch_bounds__(128) void dftw_k(float* __restrict__ X,
                                              const float* __restrict__ EAt,
                                              float* __restrict__ T,
                                              const float* __restrict__ statsl,
                                              const float* __restrict__ g,
                                              const float* __restrict__ bt,
                                              int fuse) {
    __shared__ __align__(16) float Xs[32 * 68];   // transposed [k][m]
    __shared__ __align__(16) float Est[40 * 32];  // [n][k] chunk
    int tid = threadIdx.x;
    int tm = tid >> 3, tn = tid & 7;
    int row0 = blockIdx.x << 6;
    float sc = 1.f, sh = 0.f;
    if (fuse) {
        int c = (row0 >> 8) & 63;
        float ssum = statsl[c] + statsl[128 + c] + statsl[256 + c] + statsl[384 + c];
        float ssq  = statsl[64 + c] + statsl[192 + c] + statsl[320 + c] + statsl[448 + c];
        float mean = ssum * (1.f / 524288.f);
        float var = ssq * (1.f / 524288.f) - mean * mean;
        sc = g[c] * rsqrtf(var + 1e-5f);
        sh = bt[c] - mean * sc;
    }
    float acc[4][5];
#pragma unroll
    for (int i = 0; i < 4; ++i)
#pragma unroll
        for (int j = 0; j < 5; ++j) acc[i][j] = 0.f;

#pragma unroll 1
    for (int kc = 0; kc < 256; kc += 32) {
        __syncthreads();
#pragma unroll
        for (int r = 0; r < 4; ++r) {
            int m = tm + (r << 4);
            float4 v = *(const float4*)&X[(row0 + m) * 256 + kc + (tn << 2)];
            if (fuse) {
                v.x = fmaxf(fmaf(v.x, sc, sh), 0.f);
                v.y = fmaxf(fmaf(v.y, sc, sh), 0.f);
                v.z = fmaxf(fmaf(v.z, sc, sh), 0.f);
                v.w = fmaxf(fmaf(v.w, sc, sh), 0.f);
                *(float4*)&X[(row0 + m) * 256 + kc + (tn << 2)] = v;
            }
            int kb = tn << 2;
            Xs[(kb + 0) * 68 + m] = v.x;
            Xs[(kb + 1) * 68 + m] = v.y;
            Xs[(kb + 2) * 68 + m] = v.z;
            Xs[(kb + 3) * 68 + m] = v.w;
        }
        for (int i = tid; i < 1280; i += 128) Est[i] = EAt[((i >> 5) << 8) + kc + (i & 31)];
        __syncthreads();
#pragma unroll 1
        for (int k4 = 0; k4 < 8; ++k4) {
            float4 e0 = *(const float4*)&Est[(tn * 5 + 0) * 32 + (k4 << 2)];
            float4 e1 = *(const float4*)&Est[(tn * 5 + 1) * 32 + (k4 << 2)];
            float4 e2 = *(const float4*)&Est[(tn * 5 + 2) * 32 + (k4 << 2)];
            float4 e3 = *(const float4*)&Est[(tn * 5 + 3) * 32 + (k4 << 2)];
            float4 e4 = *(const float4*)&Est[(tn * 5 + 4) * 32 + (k4 << 2)];
#pragma unroll
            for (int c2 = 0; c2 < 4; ++c2) {
                float4 a = *(const float4*)&Xs[((k4 << 2) + c2) * 68 + (tm << 2)];
                float ev0 = ((const float*)&e0)[c2];
                float ev1 = ((const float*)&e1)[c2];
                float ev2 = ((const float*)&e2)[c2];
                float ev3 = ((const float*)&e3)[c2];
                float ev4 = ((const float*)&e4)[c2];
                acc[0][0] += a.x * ev0; acc[1][0] += a.y * ev0; acc[2][0] += a.z * ev0; acc[3][0] += a.w * ev0;
                acc[0][1] += a.x * ev1; acc[1][1] += a.y * ev1; acc[2][1] += a.z * ev1; acc[3][1] += a.w * ev1;
                acc[0][2] += a.x * ev2; acc[1][2] += a.y * ev2; acc[2][2] += a.z * ev2; acc[3][2] += a.w * ev2;
                acc[0][3] += a.x * ev3; acc[1][3] += a.y * ev3; acc[2][3] += a.z * ev3; acc[3][3] += a.w * ev3;
                acc[0][4] += a.x * ev4; acc[1][4] += a.y * ev4; acc[2][4] += a.z * ev4; acc[3][4] += a.w * ev4;
            }
        }
    }
#pragma unroll
    for (int i = 0; i < 4; ++i) {
        int row = row0 + (tm << 2) + i;
#pragma unroll
        for (int j = 0; j < 5; ++j) T[row * 40 + tn * 5 + j] = acc[i][j];
    }
}

// --------------- stage B: DFT along H (256 -> 40 rows), 4-way h-split
__global__ __launch_bounds__(1024) void dfth_k(const float* __restrict__ T,
                                               const float* __restrict__ ct, const float* __restrict__ st,
                                               float* __restrict__ XF) {
    __shared__ __align__(16) float Ts[10240];
    __shared__ float cts[256], sts[256];
    __shared__ float part[3][1600];
    int tid = threadIdx.x;
    int bc = blockIdx.x;
    for (int i = tid; i < 10240; i += 1024) Ts[i] = T[bc * 10240 + i];
    if (tid < 256) { cts[tid] = ct[tid]; sts[tid] = st[tid]; }
    __syncthreads();
    int gq = tid >> 8, t2 = tid & 255;
    float ar0 = 0, ai0 = 0, ar1 = 0, ai1 = 0, ar2 = 0, ai2 = 0, ar3 = 0, ai3 = 0;
    int kxi = t2 / 5, kyg = t2 % 5;
    if (t2 < 200) {
        int kxa = kxi < 20 ? kxi : kxi + 216;
        int h0 = gq << 6;
        int r = (kxa * h0) & 255;
#pragma unroll 1
        for (int hh = 0; hh < 64; ++hh) {
            int h = h0 + hh;
            float cc = cts[r], sv = sts[r];
            r = (r + kxa) & 255;
            float4 v0 = *(const float4*)&Ts[h * 40 + (kyg << 3)];
            float4 v1 = *(const float4*)&Ts[h * 40 + (kyg << 3) + 4];
            ar0 += v0.x * cc + v0.y * sv;  ai0 += v0.y * cc - v0.x * sv;
            ar1 += v0.z * cc + v0.w * sv;  ai1 += v0.w * cc - v0.z * sv;
            ar2 += v1.x * cc + v1.y * sv;  ai2 += v1.y * cc - v1.x * sv;
            ar3 += v1.z * cc + v1.w * sv;  ai3 += v1.w * cc - v1.z * sv;
        }
        if (gq) {
            float* p = &part[gq - 1][t2 * 8];
            p[0] = ar0; p[1] = ai0; p[2] = ar1; p[3] = ai1;
            p[4] = ar2; p[5] = ai2; p[6] = ar3; p[7] = ai3;
        }
    }
    __syncthreads();
    if (gq == 0 && t2 < 200) {
#pragma unroll
        for (int j = 0; j < 3; ++j) {
            const float* p = &part[j][t2 * 8];
            ar0 += p[0]; ai0 += p[1]; ar1 += p[2]; ai1 += p[3];
            ar2 += p[4]; ai2 += p[5]; ar3 += p[6]; ai3 += p[7];
        }
        int b = bc >> 6, c = bc & 63;
        const float s = 1.f / 256.f;
        int A = (b * 40 + kxi) * 20 + (kyg << 2);
        float2* O = (float2*)XF;
        O[(A + 0) * 64 + c] = make_float2(ar0 * s, ai0 * s);
        O[(A + 1) * 64 + c] = make_float2(ar1 * s, ai1 * s);
        O[(A + 2) * 64 + c] = make_float2(ar2 * s, ai2 * s);
        O[(A + 3) * 64 + c] = make_float2(ar3 * s, ai3 * s);
    }
}

// ---------------------------------------------------------------- mode einsum
__global__ __launch_bounds__(512) void eins_t_k(const float* __restrict__ XF,
                                                const unsigned int* __restrict__ wtl,
                                                float* __restrict__ YF) {
    __shared__ float xfs[1024];
    int tid = threadIdx.x;
    int x = blockIdx.x / 20, y = blockIdx.x % 20;
    for (int i = tid; i < 1024; i += 512) {
        int b = i >> 7, rr = i & 127;
        xfs[i] = XF[(b * 40 + x) * 2560 + y * 128 + rr];
    }
    __syncthreads();
    int b = tid >> 6, o = tid & 63;
    const unsigned int* wp = wtl + (size_t)(((x < 20 ? 0 : 400) + (x % 20) * 20 + y)) * 4096 + o;
    float ar = 0.f, ai = 0.f;
#pragma unroll 8
    for (int i = 0; i < 64; ++i) {
        unsigned int wv = wp[i << 6];
        float wr = __uint_as_float(wv << 16);
        float wi = __uint_as_float(wv & 0xffff0000u);
        float xr = xfs[(b << 7) + (i << 1)];
        float xi = xfs[(b << 7) + (i << 1) + 1];
        ar += xr * wr - xi * wi;
        ai += xr * wi + xi * wr;
    }
    ((float2*)YF)[((b * 40 + x) * 20 + y) * 64 + o] = make_float2(ar, ai);
}

__global__ __launch_bounds__(512) void eins_k(const float* __restrict__ XF,
                                              const float* __restrict__ w1, const float* __restrict__ w2,
                                              float* __restrict__ YF) {
    __shared__ float xfs[1024];
    int tid = threadIdx.x;
    int x = blockIdx.x / 20, y = blockIdx.x % 20;
    for (int i = tid; i < 1024; i += 512) {
        int b = i >> 7, rr = i & 127;
        xfs[i] = XF[(b * 40 + x) * 2560 + y * 128 + rr];
    }
    __syncthreads();
    int b = tid >> 6, o = tid & 63;
    const float* wp = (x < 20) ? (w1 + (x * 20 + y) * 2) : (w2 + ((x - 20) * 20 + y) * 2);
    float ar = 0.f, ai = 0.f;
#pragma unroll 8
    for (int i = 0; i < 64; ++i) {
        float2 wv = *(const float2*)&wp[(i * 64 + o) * 800];
        float xr = xfs[(b << 7) + (i << 1)];
        float xi = xfs[(b << 7) + (i << 1) + 1];
        ar += xr * wv.x - xi * wv.y;
        ai += xr * wv.y + xi * wv.x;
    }
    ((float2*)YF)[((b * 40 + x) * 20 + y) * 64 + o] = make_float2(ar, ai);
}

// ------------------------------------ stage C: inverse (full complex) DFT along H
__global__ __launch_bounds__(256) void idfth_k(const float* __restrict__ YF,
                                               const float* __restrict__ ct, const float* __restrict__ st,
                                               float* __restrict__ Z) {
    __shared__ __align__(16) float yfs[1600];
    __shared__ float cts[256], sts[256];
    int tid = threadIdx.x;
    int bc = blockIdx.x;
    int b = bc >> 6, co = bc & 63;
    for (int i = tid; i < 800; i += 256) {
        int kx = i / 20, ky = i % 20;
        float2 v = ((const float2*)YF)[((b * 40 + kx) * 20 + ky) * 64 + co];
        yfs[kx * 40 + 2 * ky] = v.x;
        yfs[kx * 40 + 2 * ky + 1] = v.y;
    }
    cts[tid] = ct[tid]; sts[tid] = st[tid];
    __syncthreads();
    int h = tid;
    float accr[20], acci[20];
#pragma unroll
    for (int q = 0; q < 20; ++q) { accr[q] = 0.f; acci[q] = 0.f; }
#pragma unroll 1
    for (int kxi = 0; kxi < 40; ++kxi) {
        int kxa = kxi < 20 ? kxi : kxi + 216;
        int r = (kxa * h) & 255;
        float cc = cts[r], sv = sts[r];
#pragma unroll
        for (int q = 0; q < 10; ++q) {
            float4 v = *(const float4*)&yfs[kxi * 40 + (q << 2)];
            accr[2 * q]     += v.x * cc - v.y * sv;  acci[2 * q]     += v.x * sv + v.y * cc;
            accr[2 * q + 1] += v.z * cc - v.w * sv;  acci[2 * q + 1] += v.z * sv + v.w * cc;
        }
    }
    const float s = 1.f / 16.f;
    int base = (bc * 256 + h) * 40;
#pragma unroll
    for (int q = 0; q < 10; ++q) {
        float4 o4;
        o4.x = accr[2 * q] * s;     o4.y = acci[2 * q] * s;
        o4.z = accr[2 * q + 1] * s; o4.w = acci[2 * q + 1] * s;
        *(float4*)&Z[base + (q << 2)] = o4;
    }
}

// ------------------- stage D fused with 1x1 conv + bias + BN-stats accumulation
#define FMA2(I, AV, J, B4) \
    acc[I][J].x += (AV) * B4.x; acc[I][J].y += (AV) * B4.y; \
    acc[I][J].z += (AV) * B4.z; acc[I][J].w += (AV) * B4.w;

#define FMA_COL(J, B4) \
    FMA2(0, a0.x, J, B4) FMA2(1, a0.y, J, B4) FMA2(2, a0.z, J, B4) FMA2(3, a0.w, J, B4) \
    FMA2(4, a1.x, J, B4) FMA2(5, a1.y, J, B4) FMA2(6, a1.z, J, B4) FMA2(7, a1.w, J, B4)

#define FMA_COLU(J, B4) \
    FMA2(0, au0.x, J, B4) FMA2(1, au0.y, J, B4) FMA2(2, au0.z, J, B4) FMA2(3, au0.w, J, B4) \
    FMA2(4, au1.x, J, B4) FMA2(5, au1.y, J, B4) FMA2(6, au1.z, J, B4) FMA2(7, au1.w, J, B4)

#define FMA_COLD(J, B4) \
    FMA2(0, ad0.x, J, B4) FMA2(1, ad0.y, J, B4) FMA2(2, ad0.z, J, B4) FMA2(3, ad0.w, J, B4) \
    FMA2(4, ad1.x, J, B4) FMA2(5, ad1.y, J, B4) FMA2(6, ad1.z, J, B4) FMA2(7, ad1.w, J, B4)

__global__ __launch_bounds__(256) void speclin_k(const float* __restrict__ hin,
                                                 const float* __restrict__ Z,
                                                 const float* __restrict__ cwTl,
                                                 const float* __restrict__ Tw,
                                                 const float* __restrict__ cbl,
                                                 float* __restrict__ pre,
                                                 float* __restrict__ statsl) {
    __shared__ __align__(16) float As[64 * 68];      // cw^T [i][o] (17.4 KB)
    __shared__ __align__(16) float Zs[80 * 64];      // [r*40+kp][o] (20 KB)
    __shared__ __align__(16) float Bs[2][4096];      // dbuf 8k x 512n (32 KB)
    int tid = threadIdx.x;
    int bid = blockIdx.x;
    int b = bid >> 7, hp = bid & 127;
    int h0 = hp << 1;
    int to = tid >> 5, tw = tid & 31;
    int o0 = to << 3;

#pragma unroll
    for (int t = 0; t < 4; ++t) {
        int i4 = tid + (t << 8);                     // 0..1023
        float4 v = *(const float4*)&cwTl[i4 << 2];
        float* d = &As[(i4 >> 4) * 68 + ((i4 & 15) << 2)];
        d[0] = v.x; d[1] = v.y; d[2] = v.z; d[3] = v.w;
    }
#pragma unroll
    for (int t = 0; t < 5; ++t) {
        int i4 = tid + (t << 8);                     // 0..1279
        int q = i4 % 10;
        int u = i4 / 10;                             // 0..127
        int o = u & 63, r = u >> 6;
        float4 v = *(const float4*)&Z[(((b << 6) + o) * 256 + h0 + r) * 40 + (q << 2)];
        int base = ((r * 40 + (q << 2)) << 6) + o;
        Zs[base]       = v.x;
        Zs[base + 64]  = v.y;
        Zs[base + 128] = v.z;
        Zs[base + 192] = v.w;
    }
    const float* hrow = hin + (size_t)((((b << 6) << 8) + h0) << 8);
#pragma unroll
    for (int t = 0; t < 4; ++t) {                    // Bs chunk 0 via DMA
        int i4 = tid + (t << 8);                     // 0..1023
        int k = i4 >> 7, n4 = i4 & 127, r = n4 >> 6, w4 = n4 & 63;
        gll16(&hrow[(k << 16) + (r << 8) + (w4 << 2)], &Bs[0][i4 << 2]);
    }
    __syncthreads();

    float4 acc[8][4];
#pragma unroll
    for (int i = 0; i < 8; ++i)
#pragma unroll
        for (int j = 0; j < 4; ++j) acc[i][j] = make_float4(0.f, 0.f, 0.f, 0.f);

    int cur = 0;
#pragma unroll 1
    for (int ch = 0; ch < 8; ++ch) {
        if (ch < 7) {
#pragma unroll
            for (int t = 0; t < 4; ++t) {
                int i4 = tid + (t << 8);
                int k = i4 >> 7, n4 = i4 & 127, r = n4 >> 6, w4 = n4 & 63;
                gll16(&hrow[((((ch + 1) << 3) + k) << 16) + (r << 8) + (w4 << 2)],
                      &Bs[cur ^ 1][i4 << 2]);
            }
        } else {
#pragma unroll
            for (int t = 0; t < 2; ++t) {
                int i4 = tid + (t << 8);
                gll16(&Tw[i4 << 2], &Bs[cur ^ 1][i4 << 2]);
            }
        }
        const float* Bc = Bs[cur];
        const float* Ac = &As[(ch << 3) * 68 + o0];
#pragma unroll 1
        for (int kk = 0; kk < 8; ++kk) {
            float4 a0 = *(const float4*)&Ac[kk * 68];
            float4 a1 = *(const float4*)&Ac[kk * 68 + 4];
            float4 b0 = *(const float4*)&Bc[(kk << 9) + (tw << 2)];
            float4 b1 = *(const float4*)&Bc[(kk << 9) + 128 + (tw << 2)];
            FMA_COL(0, b0)
            FMA_COL(1, b1)
            float4 b2 = *(const float4*)&Bc[(kk << 9) + 256 + (tw << 2)];
            float4 b3 = *(const float4*)&Bc[(kk << 9) + 384 + (tw << 2)];
            FMA_COL(2, b2)
            FMA_COL(3, b3)
        }
        __syncthreads();
        cur ^= 1;
    }

#pragma unroll 1
    for (int ch = 0; ch < 5; ++ch) {
        if (ch < 4) {
#pragma unroll
            for (int t = 0; t < 2; ++t) {
                int i4 = tid + (t << 8);
                gll16(&Tw[(((ch + 1) << 3) << 8) + (i4 << 2)], &Bs[cur ^ 1][i4 << 2]);
            }
        }
        const float* Bc = Bs[cur];
#pragma unroll 1
        for (int kk = 0; kk < 8; ++kk) {
            int kp = (ch << 3) + kk;
            float4 b0 = *(const float4*)&Bc[(kk << 8) + (tw << 2)];
            float4 b1 = *(const float4*)&Bc[(kk << 8) + 128 + (tw << 2)];
            float4 au0 = *(const float4*)&Zs[(kp << 6) + o0];
            float4 au1 = *(const float4*)&Zs[(kp << 6) + o0 + 4];
            FMA_COLU(0, b0)
            FMA_COLU(1, b1)
            float4 ad0 = *(const float4*)&Zs[((40 + kp) << 6) + o0];
            float4 ad1 = *(const float4*)&Zs[((40 + kp) << 6) + o0 + 4];
            FMA_COLD(2, b0)
            FMA_COLD(3, b1)
        }
        __syncthreads();
        cur ^= 1;
    }

    float* srep = statsl + ((bid & 3) << 7);
#pragma unroll
    for (int i = 0; i < 8; ++i) {
        float cbv = cbl[o0 + i];
        float sum = 0.f, sq = 0.f;
#pragma unroll
        for (int j = 0; j < 4; ++j) {
            float4 v = acc[i][j];
            v.x += cbv; v.y += cbv; v.z += cbv; v.w += cbv;
            int row = h0 + (j >> 1);
            int wc = ((j & 1) << 7) + (tw << 2);
            *(float4*)&pre[(size_t)((((b << 6) + o0 + i) << 8) + row) * 256 + wc] = v;
            sum += v.x + v.y + v.z + v.w;
            sq  += v.x * v.x + v.y * v.y + v.z * v.z + v.w * v.w;
        }
        sum += __shfl_xor(sum, 1);  sq += __shfl_xor(sq, 1);
        sum += __shfl_xor(sum, 2);  sq += __shfl_xor(sq, 2);
        sum += __shfl_xor(sum, 4);  sq += __shfl_xor(sq, 4);
        sum += __shfl_xor(sum, 8);  sq += __shfl_xor(sq, 8);
        sum += __shfl_xor(sum, 16); sq += __shfl_xor(sq, 16);
        if ((tid & 31) == 0) {
            atomicAdd(&srep[o0 + i], sum);
            atomicAdd(&srep[64 + o0 + i], sq);
        }
    }
}

// ----------------- fc1+relu+fc2, layer-3 BN folded into fc1 weights/bias
__global__ __launch_bounds__(256, 2) void fc12_k(const float* __restrict__ hin,
                                                 const float* __restrict__ statsl,
                                                 const float* __restrict__ g,
                                                 const float* __restrict__ bt,
                                                 const float* __restrict__ w1, const float* __restrict__ b1,
                                                 const float* __restrict__ w2, const float* __restrict__ b2,
                                                 float* __restrict__ out) {
    __shared__ __align__(16) float As[64 * 128];   // sc_c * fc1_w[c][d]
    __shared__ __align__(16) float Bs[2][2048];
    __shared__ float scs[64], shs[64], bias2[128];
    __shared__ __align__(16) float red[4 * 256];
    int tid = threadIdx.x;
    int bh = blockIdx.x;
    int b = bh >> 8, h = bh & 255;
    int to = tid >> 4, tw = tid & 15;
    int d0 = to << 3;

    if (tid < 64) {
        float ssum = statsl[tid] + statsl[128 + tid] + statsl[256 + tid] + statsl[384 + tid];
        float ssq  = statsl[64 + tid] + statsl[192 + tid] + statsl[320 + tid] + statsl[448 + tid];
        float mean = ssum * (1.f / 524288.f);
        float var = ssq * (1.f / 524288.f) - mean * mean;
        float s = g[tid] * rsqrtf(var + 1e-5f);
        scs[tid] = s; shs[tid] = bt[tid] - mean * s;
    }
    __syncthreads();
    for (int i = tid; i < 8192; i += 256) As[i] = w1[i] * scs[i >> 7];
    if (tid < 128) {
        float a = b1[tid];
        for (int c = 0; c < 64; ++c) a += shs[c] * w1[c * 128 + tid];
        bias2[tid] = a;
    }
    const float* hrow = hin + ((size_t)(((b << 6) << 8) + h) << 8);
#pragma unroll
    for (int t = 0; t < 2; ++t) {
        int i4 = tid + (t << 8);
        gll16(&hrow[((i4 >> 6) << 16) + ((i4 & 63) << 2)], &Bs[0][i4 << 2]);
    }
    __syncthreads();

    float4 acc[8][4];
#pragma unroll
    for (int i = 0; i < 8; ++i)
#pragma unroll
        for (int j = 0; j < 4; ++j) acc[i][j] = make_float4(0.f, 0.f, 0.f, 0.f);

    int cur = 0;
#pragma unroll 1
    for (int ch = 0; ch < 8; ++ch) {
        if (ch < 7) {
#pragma unroll
            for (int t = 0; t < 2; ++t) {
                int i4 = tid + (t << 8);
                int k = i4 >> 6, w4 = (i4 & 63) << 2;
                gll16(&hrow[((((ch + 1) << 3) + k) << 16) + w4], &Bs[cur ^ 1][i4 << 2]);
            }
        }
        const float* Bc = Bs[cur];
#pragma unroll 2
        for (int kk = 0; kk < 8; ++kk) {
            int gk = (ch << 3) + kk;
            float4 a0 = *(const float4*)&As[(gk << 7) + d0];
            float4 a1 = *(const float4*)&As[(gk << 7) + d0 + 4];
            float4 b0 = *(const float4*)&Bc[(kk << 8) + (tw << 2)];
            float4 b1 = *(const float4*)&Bc[(kk << 8) + 64 + (tw << 2)];
            FMA_COL(0, b0)
            FMA_COL(1, b1)
            float4 b2 = *(const float4*)&Bc[(kk << 8) + 128 + (tw << 2)];
            float4 b3 = *(const float4*)&Bc[(kk << 8) + 192 + (tw << 2)];
            FMA_COL(2, b2)
            FMA_COL(3, b3)
        }
        __syncthreads();
        cur ^= 1;
    }

    float bb[8], wv[8];
#pragma unroll
    for (int i = 0; i < 8; ++i) { bb[i] = bias2[d0 + i]; wv[i] = w2[d0 + i]; }
    float4 p[4];
#pragma unroll
    for (int j = 0; j < 4; ++j) {
        float4 v = make_float4(0.f, 0.f, 0.f, 0.f);
#pragma unroll
        for (int i = 0; i < 8; ++i) {
            v.x += fmaxf(acc[i][j].x + bb[i], 0.f) * wv[i];
            v.y += fmaxf(acc[i][j].y + bb[i], 0.f) * wv[i];
            v.z += fmaxf(acc[i][j].z + bb[i], 0.f) * wv[i];
            v.w += fmaxf(acc[i][j].w + bb[i], 0.f) * wv[i];
        }
        v.x += __shfl_xor(v.x, 16); v.y += __shfl_xor(v.y, 16);
        v.z += __shfl_xor(v.z, 16); v.w += __shfl_xor(v.w, 16);
        v.x += __shfl_xor(v.x, 32); v.y += __shfl_xor(v.y, 32);
        v.z += __shfl_xor(v.z, 32); v.w += __shfl_xor(v.w, 32);
        p[j] = v;
    }
    int wave = tid >> 6;
    if ((tid & 63) < 16) {
#pragma unroll
        for (int j = 0; j < 4; ++j)
            *(float4*)&red[(wave << 8) + (j << 6) + (tw << 2)] = p[j];
    }
    __syncthreads();
    float s2 = b2[0] + red[tid] + red[256 + tid] + red[512 + tid] + red[768 + tid];
    out[(b * 256 + h) * 256 + tid] = s2;
}

// ------------------------------------------------------------------- launcher
extern "C" void kernel_launch(void* const* d_in, const int* in_sizes, int n_in,
                              void* d_out, int out_size, void* d_ws, size_t ws_size,
                              hipStream_t stream) {
    (void)in_sizes; (void)n_in; (void)out_size;
    const float* x     = (const float*)d_in[0];
    const float* fc0_w = (const float*)d_in[1];
    const float* fc0_b = (const float*)d_in[2];
    const float* sw1   = (const float*)d_in[3];
    const float* sw2   = (const float*)d_in[4];
    const float* cw    = (const float*)d_in[5];
    const float* cb    = (const float*)d_in[6];
    const float* bng   = (const float*)d_in[7];
    const float* bnb   = (const float*)d_in[8];
    const float* fc1_w = (const float*)d_in[9];
    const float* fc1_b = (const float*)d_in[10];
    const float* fc2_w = (const float*)d_in[11];
    const float* fc2_b = (const float*)d_in[12];
    float* out = (float*)d_out;

    float* ws = (float*)d_ws;
    float* hbuf   = ws;                       // 33,554,432  (in-place activations)
    float* tz     = hbuf + 33554432;          // 5,242,880
    float* xf     = tz + 5242880;             // 819,200
    float* yf     = xf + 819200;              // 819,200
    float* costab = yf + 819200;              // 256
    float* sintab = costab + 256;             // 256
    float* EAt    = sintab + 256;             // 10,240
    float* Tw     = EAt + 10240;              // 10,240
    float* cwT    = Tw + 10240;               // 16,384
    float* stats  = cwT + 16384;              // 2,048  (4 layers x 4 replicas x 128)
    unsigned* wt  = (unsigned*)(stats + 2048);         // 13,107,200 u32 (optional)

    size_t base_floats = 40473600 + 2048;     // through stats
    int use_wt = (ws_size >= (base_floats + 13107200ull) * 4ull) ? 1 : 0;

    init_k<<<153, 256, 0, stream>>>(cw, costab, sintab, EAt, Tw, cwT, stats);
    if (use_wt) wtrans_k<<<3200, 256, 0, stream>>>(sw1, sw2, wt);
    fc0_k<<<2048, 256, 0, stream>>>(x, fc0_w, fc0_b, hbuf);

    for (int l = 0; l < 4; ++l) {
        if (l == 0)
            dftw_k<<<2048, 128, 0, stream>>>(hbuf, EAt, tz, stats, bng, bnb, 0);
        else
            dftw_k<<<2048, 128, 0, stream>>>(hbuf, EAt, tz, stats + (l - 1) * 512,
                                             bng + (l - 1) * 64, bnb + (l - 1) * 64, 1);
        dfth_k<<<512, 1024, 0, stream>>>(tz, costab, sintab, xf);
        if (use_wt)
            eins_t_k<<<800, 512, 0, stream>>>(xf, wt + (size_t)l * 2 * 400 * 4096, yf);
        else
            eins_k<<<800, 512, 0, stream>>>(xf, sw1 + l * 3276800, sw2 + l * 3276800, yf);
        idfth_k<<<512, 256, 0, stream>>>(yf, costab, sintab, tz);
        speclin_k<<<1024, 256, 0, stream>>>(hbuf, tz, cwT + l * 4096, Tw, cb + l * 64,
                                            hbuf, stats + l * 512);
    }
    fc12_k<<<2048, 256, 0, stream>>>(hbuf, stats + 3 * 512, bng + 3 * 64, bnb + 3 * 64,
                                     fc1_w, fc1_b, fc2_w, fc2_b, out);
}